// Round 3
// baseline (46463.403 us; speedup 1.0000x reference)
//
#include <hip/hip_runtime.h>
#include <hip/hip_bf16.h>

#define NN 10000      // nodes
#define NE 160000     // edges
#define TS 32         // timesteps
#define HID 256
#define NFEAT 192
#define TTEACH 24

typedef unsigned short u16;
typedef unsigned int u32;

__device__ __forceinline__ float bf2f(u16 u){
    u32 v = ((u32)u) << 16;
    union { u32 i; float f; } c; c.i = v; return c.f;
}
__device__ __forceinline__ u16 f2bf(float f){
    union { float f; u32 i; } c; c.f = f;
    u32 i = c.i;
    u32 lsb = (i >> 16) & 1u;
    i += 0x7fffu + lsb;
    return (u16)(i >> 16);
}

__global__ void fill_f32(float* p, float v, int n){
    int i = blockIdx.x * 256 + threadIdx.x;
    if (i < n) p[i] = v;
}
__global__ void fill_i32(int* p, int v, int n){
    int i = blockIdx.x * 256 + threadIdx.x;
    if (i < n) p[i] = v;
}

// ---------- runtime dtype detection ----------
// z ~ uniform[0,1). As bf16: every u16 <= 0x3F80 (1.0). As fp32: even u16
// words are low mantissa bits (uniform junk), ~75% >= 0x4000. 128 samples.
__global__ void detect_f32(const u16* __restrict__ zraw, int* __restrict__ flag){
    int c = 0;
    for (int i = 0; i < 128; i++) if (zraw[2*i] >= 0x4000) c++;
    *flag = (c > 8) ? 1 : 0;
}
// convert any float input to canonical fp32
__global__ void conv_f32(const void* __restrict__ in, float* __restrict__ outp,
                         int n, const int* __restrict__ flag){
    int i = blockIdx.x * 256 + threadIdx.x;
    if (i >= n) return;
    if (*flag) outp[i] = ((const float*)in)[i];
    else       outp[i] = bf2f(((const u16*)in)[i]);
}

// edge_index: int32 [2,E] or int64 [2,E]. If int64 (values < 2^31), every
// odd int32 word is 0; impossible for 32 consecutive random int32 indices.
__global__ void detect_i64(const int* __restrict__ ei_raw, int* __restrict__ flag){
    int zz = 0;
    #pragma unroll
    for (int i = 0; i < 32; i++) zz |= ei_raw[2*i + 1];
    *flag = (zz == 0) ? 1 : 0;
}
__global__ void copy_edges(const int* __restrict__ ei_raw, const int* __restrict__ flag,
                           int* __restrict__ src, int* __restrict__ dst){
    int e = blockIdx.x * 256 + threadIdx.x;
    if (e >= NE) return;
    int st = (*flag) ? 2 : 1;
    src[e] = ei_raw[(size_t)e * st];
    dst[e] = ei_raw[((size_t)NE + e) * st];
}

__global__ void degree_k(const int* __restrict__ dst, int* __restrict__ cnt, int n){
    int e = blockIdx.x * 256 + threadIdx.x;
    if (e < n) atomicAdd(&cnt[dst[e]], 1);
}
__global__ void invcnt_k(const int* __restrict__ cnt, float* __restrict__ inv, int n){
    int i = blockIdx.x * 256 + threadIdx.x;
    if (i < n) inv[i] = 1.0f / fmaxf((float)cnt[i], 1.0f);
}
// WhhT[h][j] = Whh[j][h]   (Whh: [768][256] fp32 canonical)
__global__ void transpose_whh(const float* __restrict__ Whh, float* __restrict__ WhhT){
    int idx = blockIdx.x * 256 + threadIdx.x;
    if (idx < 768 * 256){
        int j = idx / 256, h = idx % 256;
        WhhT[h * 768 + j] = Whh[idx];
    }
}

// Generic fp32 tiled GEMM: C[M,N] = epi(A[M,K] @ B + bias)
// MODE 0: fh = relu(h @ Wf + bf)          B std [K][N]
// MODE 1: AB = fh @ W1' (+b1 on A-part)   B via W1 indexing
// MODE 2: gh = (m_acc*inv) @ WhhT + bhh   B std [K][N]
template<int MODE>
__global__ __launch_bounds__(256, 2) void gemm64(
    const float* __restrict__ A, const float* __restrict__ Bw,
    const float* __restrict__ bias, float* __restrict__ Cf,
    const float* __restrict__ rowscale, int M, int Kd, int Nd)
{
    __shared__ float As[32][68];
    __shared__ float Bs[32][68];
    const int m0 = blockIdx.x * 64;
    const int n0 = blockIdx.y * 64;
    const int tid = threadIdx.x;

    int kblk = 0, part = 0;
    if (MODE == 1){ kblk = n0 / 512; part = (n0 % 512) / 256; }

    float acc[4][4] = {};
    const int ea  = tid >> 2;     // 0..63 staging row
    const int seg = tid & 3;      // 0..3
    const int row = m0 + ea;
    float rs = 1.0f;
    if (MODE == 2 && row < M) rs = rowscale[row];

    for (int k0 = 0; k0 < Kd; k0 += 32){
        // stage A (64 x 32)
        {
            float av[8];
            if (row < M){
                const float4* p = reinterpret_cast<const float4*>(&A[(size_t)row * Kd + k0 + seg * 8]);
                float4 x0 = p[0], x1 = p[1];
                av[0]=x0.x; av[1]=x0.y; av[2]=x0.z; av[3]=x0.w;
                av[4]=x1.x; av[5]=x1.y; av[6]=x1.z; av[7]=x1.w;
            } else {
                #pragma unroll
                for (int i=0;i<8;i++) av[i]=0.f;
            }
            if (MODE == 2){
                #pragma unroll
                for (int i=0;i<8;i++) av[i] *= rs;
            }
            #pragma unroll
            for (int i=0;i<8;i++) As[seg*8+i][ea] = av[i];
        }
        // stage B (32 x 64)
        {
            #pragma unroll
            for (int i=0;i<8;i++){
                int lin = tid + i * 256;   // 0..2047
                int r = lin >> 6, c = lin & 63;
                int f = k0 + r, cg = n0 + c;
                float w;
                if (MODE == 1){
                    w = Bw[(size_t)kblk * (384*256) + (size_t)(part*192 + f) * 256 + (cg & 255)];
                } else {
                    w = Bw[(size_t)f * Nd + cg];
                }
                Bs[r][c] = w;
            }
        }
        __syncthreads();
        const int e0 = (tid >> 4) * 4;
        const int j0 = (tid & 15) * 4;
        #pragma unroll
        for (int kk = 0; kk < 32; kk++){
            float4 a = *reinterpret_cast<const float4*>(&As[kk][e0]);
            float4 b = *reinterpret_cast<const float4*>(&Bs[kk][j0]);
            float av[4] = {a.x, a.y, a.z, a.w};
            float bv[4] = {b.x, b.y, b.z, b.w};
            #pragma unroll
            for (int i=0;i<4;i++)
                #pragma unroll
                for (int j=0;j<4;j++)
                    acc[i][j] += av[i] * bv[j];
        }
        __syncthreads();
    }
    // epilogue
    const int e0 = (tid >> 4) * 4;
    const int j0 = (tid & 15) * 4;
    #pragma unroll
    for (int i=0;i<4;i++){
        int r = m0 + e0 + i;
        if (r >= M) continue;
        #pragma unroll
        for (int jj=0;jj<4;jj++){
            int c = n0 + j0 + jj;
            float v = acc[i][jj];
            if (MODE == 0) v += bias[c];
            if (MODE == 1){ if (part == 0) v += bias[kblk*256 + (c & 255)]; }
            if (MODE == 2) v += bias[c];
            if (MODE == 0) v = fmaxf(v, 0.f);
            Cf[(size_t)r * Nd + c] = v;
        }
    }
}

// Edge kernel: per block 64 edges x 128 output cols, K=768.
// A-tile on the fly: z_k[e] * relu(AB[dst][k*512+j] + AB[src][k*512+256+j])
// B = W2 viewed as [768][256]. Epilogue adds sum_k z_k*b2[k][j], atomic scatter.
__global__ __launch_bounds__(256, 2) void edge_k(
    const float* __restrict__ ABf, const float* __restrict__ W2,
    const float* __restrict__ b2, const float* __restrict__ zf,
    const int* __restrict__ srcA, const int* __restrict__ dstA,
    float* __restrict__ m_acc)
{
    __shared__ float As[32][68];
    __shared__ float Bs[32][132];
    __shared__ float zc[3][64];
    __shared__ int dstc[64], srcc[64];
    const int tid = threadIdx.x;
    const int eb = blockIdx.x * 64;
    const int cb = blockIdx.y * 128;

    if (tid < 64){
        srcc[tid] = srcA[eb + tid];
        dstc[tid] = dstA[eb + tid];
    }
    int tz = tid - 64;
    if (tz >= 0 && tz < 192){
        int k = tz / 64, e = tz % 64;
        zc[k][e] = zf[(size_t)(eb + e) * 4 + 1 + k];
    }
    __syncthreads();

    float acc[4][8] = {};
    const int ea  = tid >> 2;   // 0..63
    const int seg = tid & 3;    // 0..3

    for (int kc = 0; kc < 768; kc += 32){
        const int k  = kc >> 8;                    // 0..2
        const int jb = (kc & 255) + seg * 8;
        // stage A: gather + relu + z-scale
        {
            int d = dstc[ea], s = srcc[ea];
            const float4* pa = reinterpret_cast<const float4*>(&ABf[(size_t)d * 1536 + k * 512 + jb]);
            const float4* pb = reinterpret_cast<const float4*>(&ABf[(size_t)s * 1536 + k * 512 + 256 + jb]);
            float4 a0 = pa[0], a1 = pa[1];
            float4 b0 = pb[0], b1 = pb[1];
            float av[8] = {a0.x,a0.y,a0.z,a0.w,a1.x,a1.y,a1.z,a1.w};
            float bv[8] = {b0.x,b0.y,b0.z,b0.w,b1.x,b1.y,b1.z,b1.w};
            float zk = zc[k][ea];
            #pragma unroll
            for (int i=0;i<8;i++){
                float v = av[i] + bv[i];
                As[seg*8 + i][ea] = zk * fmaxf(v, 0.f);
            }
        }
        // stage B: W2 rows kc..kc+31, cols cb..cb+127
        {
            #pragma unroll
            for (int i=0;i<8;i++){
                int lin = tid * 2 + i * 512;  // even, covers 0..4094
                int r = lin >> 7, c = lin & 127;
                const float* p = &W2[(size_t)(kc + r) * 256 + cb + c];
                Bs[r][c]     = p[0];
                Bs[r][c + 1] = p[1];
            }
        }
        __syncthreads();
        const int e0 = (tid >> 4) * 4;
        const int j0 = (tid & 15) * 8;
        #pragma unroll
        for (int kk = 0; kk < 32; kk++){
            float4 a  = *reinterpret_cast<const float4*>(&As[kk][e0]);
            float4 b0 = *reinterpret_cast<const float4*>(&Bs[kk][j0]);
            float4 b1 = *reinterpret_cast<const float4*>(&Bs[kk][j0 + 4]);
            float av[4] = {a.x, a.y, a.z, a.w};
            float bv[8] = {b0.x,b0.y,b0.z,b0.w,b1.x,b1.y,b1.z,b1.w};
            #pragma unroll
            for (int i=0;i<4;i++)
                #pragma unroll
                for (int j=0;j<8;j++)
                    acc[i][j] += av[i] * bv[j];
        }
        __syncthreads();
    }
    // epilogue: + sum_k z_k * b2[k][c], atomic scatter-add
    const int e0 = (tid >> 4) * 4;
    const int j0 = (tid & 15) * 8;
    #pragma unroll
    for (int i=0;i<4;i++){
        int eg = e0 + i;
        int d = dstc[eg];
        float z0 = zc[0][eg], z1 = zc[1][eg], z2 = zc[2][eg];
        #pragma unroll
        for (int jj=0;jj<8;jj++){
            int c = cb + j0 + jj;
            float v = acc[i][jj] + z0 * b2[c] + z1 * b2[256 + c] + z2 * b2[512 + c];
            atomicAdd(&m_acc[(size_t)d * 256 + c], v);
        }
    }
}

// GRU gates: h[n][j] = (1-z)*n + z*m  (writes h in place)
__global__ void gates_k(
    const float* __restrict__ gh, const float* __restrict__ m_acc,
    const float* __restrict__ inv_cnt, const float* __restrict__ x,
    const float* __restrict__ prev, const float* __restrict__ Wih,
    const float* __restrict__ bih, float* __restrict__ h, int t)
{
    int idx = blockIdx.x * 256 + threadIdx.x;
    if (idx >= NN * HID) return;
    int n = idx >> 8, j = idx & 255;
    float inp[6];
    if (t < TTEACH){
        #pragma unroll
        for (int c=0;c<6;c++) inp[c] = x[(size_t)n * NFEAT + t * 6 + c];
    } else {
        #pragma unroll
        for (int c=0;c<6;c++) inp[c] = prev[n * 6 + c];
    }
    float m = m_acc[idx] * inv_cnt[n];
    float gxr = bih[j], gxz = bih[256 + j], gxn = bih[512 + j];
    #pragma unroll
    for (int c=0;c<6;c++){
        gxr += inp[c] * Wih[j * 6 + c];
        gxz += inp[c] * Wih[(256 + j) * 6 + c];
        gxn += inp[c] * Wih[(512 + j) * 6 + c];
    }
    float ghr = gh[(size_t)n * 768 + j];
    float ghz = gh[(size_t)n * 768 + 256 + j];
    float ghn = gh[(size_t)n * 768 + 512 + j];
    float r  = 1.f / (1.f + __expf(-(gxr + ghr)));
    float zg = 1.f / (1.f + __expf(-(gxz + ghz)));
    float nn = tanhf(gxn + r * ghn);
    h[idx] = (1.f - zg) * nn + zg * m;
}

// mu = inputs + relu(h @ Wo + bo); writes out[:, t] (dtype per flag) and prev
__global__ void mu_k(
    const float* __restrict__ h, const float* __restrict__ Wo,
    const float* __restrict__ bo, const float* __restrict__ x,
    float* __restrict__ prev, void* __restrict__ out,
    const int* __restrict__ flag, int t)
{
    int idx = blockIdx.x * 256 + threadIdx.x;
    if (idx >= NN * 6) return;
    int n = idx / 6, c = idx % 6;
    float acc = bo[c];
    const float* hr = &h[(size_t)n * 256];
    #pragma unroll 8
    for (int j = 0; j < 256; j++) acc += hr[j] * Wo[j * 6 + c];
    float inp;
    if (t < TTEACH) inp = x[(size_t)n * NFEAT + t * 6 + c];
    else            inp = prev[idx];
    float mu = inp + fmaxf(acc, 0.f);
    if (*flag) ((float*)out)[(size_t)n * NFEAT + t * 6 + c] = mu;
    else       ((u16*)out)[(size_t)n * NFEAT + t * 6 + c] = f2bf(mu);
    prev[idx] = mu;
}

extern "C" void kernel_launch(void* const* d_in, const int* in_sizes, int n_in,
                              void* d_out, int out_size, void* d_ws, size_t ws_size,
                              hipStream_t stream)
{
    const void* x_r   = d_in[0];
    const int*  ei    = (const int*)d_in[1];
    const void* z_r   = d_in[2];
    const void* Wf_r  = d_in[3];
    const void* bf_r  = d_in[4];
    const void* W1_r  = d_in[5];
    const void* b1_r  = d_in[6];
    const void* W2_r  = d_in[7];
    const void* b2_r  = d_in[8];
    const void* Wih_r = d_in[9];
    const void* bih_r = d_in[10];
    const void* Whh_r = d_in[11];
    const void* bhh_r = d_in[12];
    const void* Wo_r  = d_in[13];
    const void* bo_r  = d_in[14];

    char* ws = (char*)d_ws;
    size_t off = 0;
    auto alloc = [&](size_t bytes){
        void* p = ws + off;
        off += (bytes + 255) & ~(size_t)255;
        return p;
    };
    float* h     = (float*)alloc((size_t)NN * HID * 4);
    float* prev  = (float*)alloc((size_t)NN * 6 * 4);
    float* fh    = (float*)alloc((size_t)NN * NFEAT * 4);
    float* ABf   = (float*)alloc((size_t)NN * 1536 * 4);
    float* m_acc = (float*)alloc((size_t)NN * HID * 4);
    float* gh    = (float*)alloc((size_t)NN * 768 * 4);
    float* invc  = (float*)alloc((size_t)NN * 4);
    int*   cnt   = (int*)  alloc((size_t)NN * 4);
    float* WhhT  = (float*)alloc((size_t)768 * 256 * 4);
    int*   src32 = (int*)  alloc((size_t)NE * 4);
    int*   dst32 = (int*)  alloc((size_t)NE * 4);
    int*   fdt   = (int*)  alloc(256);   // float dtype flag (1 = fp32)
    int*   fidx  = (int*)  alloc(256);   // index dtype flag (1 = int64)
    // canonical fp32 inputs
    float* xc   = (float*)alloc((size_t)NN * NFEAT * 4);
    float* zc   = (float*)alloc((size_t)NE * 4 * 4);
    float* Wfc  = (float*)alloc((size_t)256 * 192 * 4);
    float* bfc  = (float*)alloc(192 * 4);
    float* W1c  = (float*)alloc((size_t)3 * 384 * 256 * 4);
    float* b1c  = (float*)alloc(768 * 4);
    float* W2c  = (float*)alloc((size_t)3 * 256 * 256 * 4);
    float* b2c  = (float*)alloc(768 * 4);
    float* Wihc = (float*)alloc((size_t)768 * 6 * 4);
    float* bihc = (float*)alloc(768 * 4);
    float* Whhc = (float*)alloc((size_t)768 * 256 * 4);
    float* bhhc = (float*)alloc(768 * 4);
    float* Woc  = (float*)alloc((size_t)256 * 6 * 4);
    float* boc  = (float*)alloc(6 * 4);

    detect_f32<<<1, 1, 0, stream>>>((const u16*)z_r, fdt);
    detect_i64<<<1, 1, 0, stream>>>(ei, fidx);
    copy_edges<<<(NE + 255)/256, 256, 0, stream>>>(ei, fidx, src32, dst32);

    auto conv = [&](const void* in, float* outp, int n){
        conv_f32<<<(n + 255)/256, 256, 0, stream>>>(in, outp, n, fdt);
    };
    conv(x_r,   xc,   NN * NFEAT);
    conv(z_r,   zc,   NE * 4);
    conv(Wf_r,  Wfc,  256 * 192);
    conv(bf_r,  bfc,  192);
    conv(W1_r,  W1c,  3 * 384 * 256);
    conv(b1_r,  b1c,  768);
    conv(W2_r,  W2c,  3 * 256 * 256);
    conv(b2_r,  b2c,  768);
    conv(Wih_r, Wihc, 768 * 6);
    conv(bih_r, bihc, 768);
    conv(Whh_r, Whhc, 768 * 256);
    conv(bhh_r, bhhc, 768);
    conv(Wo_r,  Woc,  256 * 6);
    conv(bo_r,  boc,  6);

    fill_f32<<<(NN*HID + 255)/256, 256, 0, stream>>>(h, 0.f, NN*HID);
    fill_f32<<<(NN*6 + 255)/256, 256, 0, stream>>>(prev, 0.f, NN*6);
    fill_i32<<<(NN + 255)/256, 256, 0, stream>>>(cnt, 0, NN);
    degree_k<<<(NE + 255)/256, 256, 0, stream>>>(dst32, cnt, NE);
    invcnt_k<<<(NN + 255)/256, 256, 0, stream>>>(cnt, invc, NN);
    transpose_whh<<<(768*256 + 255)/256, 256, 0, stream>>>(Whhc, WhhT);

    for (int t = 0; t < TS; t++){
        // fh = relu(h @ Wf + bf)            [10000,256]x[256,192]
        gemm64<0><<<dim3(157, 3), 256, 0, stream>>>(h, Wfc, bfc, fh, nullptr, NN, 256, NFEAT);
        // AB = fh @ W1' (+b1 on A-part)     [10000,192]x[192,1536]
        gemm64<1><<<dim3(157, 24), 256, 0, stream>>>(fh, W1c, b1c, ABf, nullptr, NN, NFEAT, 1536);
        fill_f32<<<(NN*HID + 255)/256, 256, 0, stream>>>(m_acc, 0.f, NN*HID);
        // edge GEMM + scatter
        edge_k<<<dim3(2500, 2), 256, 0, stream>>>(ABf, W2c, b2c, zc, src32, dst32, m_acc);
        // gh = (m_acc * inv) @ WhhT + bhh   [10000,256]x[256,768]
        gemm64<2><<<dim3(157, 12), 256, 0, stream>>>(m_acc, WhhT, bhhc, gh, invc, NN, 256, 768);
        gates_k<<<(NN*HID + 255)/256, 256, 0, stream>>>(gh, m_acc, invc, xc, prev, Wihc, bihc, h, t);
        mu_k<<<(NN*6 + 255)/256, 256, 0, stream>>>(h, Woc, boc, xc, prev, d_out, fdt, t);
    }
}

// Round 4
// 12901.479 us; speedup vs baseline: 3.6014x; 3.6014x over previous
//
#include <hip/hip_runtime.h>
#include <hip/hip_bf16.h>

#define NN 10000      // nodes
#define NE 160000     // edges
#define TS 32         // timesteps
#define HID 256
#define NFEAT 192
#define TTEACH 24

typedef unsigned short u16;
typedef unsigned int u32;
typedef __attribute__((ext_vector_type(8))) short bf16x8;
typedef __attribute__((ext_vector_type(4))) float f32x4;

__device__ __forceinline__ float bf2f(u16 u){
    u32 v = ((u32)u) << 16;
    union { u32 i; float f; } c; c.i = v; return c.f;
}
__device__ __forceinline__ u16 f2bf(float f){
    union { float f; u32 i; } c; c.f = f;
    u32 i = c.i;
    u32 lsb = (i >> 16) & 1u;
    i += 0x7fffu + lsb;
    return (u16)(i >> 16);
}

__global__ void fill_f32(float* p, float v, int n){
    int i = blockIdx.x * 256 + threadIdx.x;
    if (i < n) p[i] = v;
}
__global__ void fill_i32(int* p, int v, int n){
    int i = blockIdx.x * 256 + threadIdx.x;
    if (i < n) p[i] = v;
}

// ---------- runtime dtype detection ----------
__global__ void detect_f32(const u16* __restrict__ zraw, int* __restrict__ flag){
    int c = 0;
    for (int i = 0; i < 128; i++) if (zraw[2*i] >= 0x4000) c++;
    *flag = (c > 8) ? 1 : 0;
}
__global__ void conv_f32(const void* __restrict__ in, float* __restrict__ outp,
                         int n, const int* __restrict__ flag){
    int i = blockIdx.x * 256 + threadIdx.x;
    if (i >= n) return;
    if (*flag) outp[i] = ((const float*)in)[i];
    else       outp[i] = bf2f(((const u16*)in)[i]);
}
__global__ void detect_i64(const int* __restrict__ ei_raw, int* __restrict__ flag){
    int zz = 0;
    #pragma unroll
    for (int i = 0; i < 32; i++) zz |= ei_raw[2*i + 1];
    *flag = (zz == 0) ? 1 : 0;
}
__global__ void copy_edges(const int* __restrict__ ei_raw, const int* __restrict__ flag,
                           int* __restrict__ src, int* __restrict__ dst){
    int e = blockIdx.x * 256 + threadIdx.x;
    if (e >= NE) return;
    int st = (*flag) ? 2 : 1;
    src[e] = ei_raw[(size_t)e * st];
    dst[e] = ei_raw[((size_t)NE + e) * st];
}

__global__ void degree_k(const int* __restrict__ dst, int* __restrict__ cnt, int n){
    int e = blockIdx.x * 256 + threadIdx.x;
    if (e < n) atomicAdd(&cnt[dst[e]], 1);
}
__global__ void invcnt_k(const int* __restrict__ cnt, float* __restrict__ inv, int n){
    int i = blockIdx.x * 256 + threadIdx.x;
    if (i < n) inv[i] = 1.0f / fmaxf((float)cnt[i], 1.0f);
}
__global__ void transpose_whh(const float* __restrict__ Whh, float* __restrict__ WhhT){
    int idx = blockIdx.x * 256 + threadIdx.x;
    if (idx < 768 * 256){
        int j = idx / 256, h = idx % 256;
        WhhT[h * 768 + j] = Whh[idx];
    }
}
// W2T[n][k] = W2[k][n] as bf16; W2 flat [768][256] fp32
__global__ void build_w2t(const float* __restrict__ W2c, u16* __restrict__ W2T){
    int idx = blockIdx.x * 256 + threadIdx.x;
    if (idx < 768 * 256){
        int k = idx / 256, n = idx % 256;
        W2T[(size_t)n * 768 + k] = f2bf(W2c[idx]);
    }
}

// Generic fp32 tiled GEMM (unchanged from round 3)
template<int MODE>
__global__ __launch_bounds__(256, 2) void gemm64(
    const float* __restrict__ A, const float* __restrict__ Bw,
    const float* __restrict__ bias, float* __restrict__ Cf,
    const float* __restrict__ rowscale, int M, int Kd, int Nd)
{
    __shared__ float As[32][68];
    __shared__ float Bs[32][68];
    const int m0 = blockIdx.x * 64;
    const int n0 = blockIdx.y * 64;
    const int tid = threadIdx.x;

    int kblk = 0, part = 0;
    if (MODE == 1){ kblk = n0 / 512; part = (n0 % 512) / 256; }

    float acc[4][4] = {};
    const int ea  = tid >> 2;
    const int seg = tid & 3;
    const int row = m0 + ea;
    float rs = 1.0f;
    if (MODE == 2 && row < M) rs = rowscale[row];

    for (int k0 = 0; k0 < Kd; k0 += 32){
        {
            float av[8];
            if (row < M){
                const float4* p = reinterpret_cast<const float4*>(&A[(size_t)row * Kd + k0 + seg * 8]);
                float4 x0 = p[0], x1 = p[1];
                av[0]=x0.x; av[1]=x0.y; av[2]=x0.z; av[3]=x0.w;
                av[4]=x1.x; av[5]=x1.y; av[6]=x1.z; av[7]=x1.w;
            } else {
                #pragma unroll
                for (int i=0;i<8;i++) av[i]=0.f;
            }
            if (MODE == 2){
                #pragma unroll
                for (int i=0;i<8;i++) av[i] *= rs;
            }
            #pragma unroll
            for (int i=0;i<8;i++) As[seg*8+i][ea] = av[i];
        }
        {
            #pragma unroll
            for (int i=0;i<8;i++){
                int lin = tid + i * 256;
                int r = lin >> 6, c = lin & 63;
                int f = k0 + r, cg = n0 + c;
                float w;
                if (MODE == 1){
                    w = Bw[(size_t)kblk * (384*256) + (size_t)(part*192 + f) * 256 + (cg & 255)];
                } else {
                    w = Bw[(size_t)f * Nd + cg];
                }
                Bs[r][c] = w;
            }
        }
        __syncthreads();
        const int e0 = (tid >> 4) * 4;
        const int j0 = (tid & 15) * 4;
        #pragma unroll
        for (int kk = 0; kk < 32; kk++){
            float4 a = *reinterpret_cast<const float4*>(&As[kk][e0]);
            float4 b = *reinterpret_cast<const float4*>(&Bs[kk][j0]);
            float av[4] = {a.x, a.y, a.z, a.w};
            float bv[4] = {b.x, b.y, b.z, b.w};
            #pragma unroll
            for (int i=0;i<4;i++)
                #pragma unroll
                for (int j=0;j<4;j++)
                    acc[i][j] += av[i] * bv[j];
        }
        __syncthreads();
    }
    const int e0 = (tid >> 4) * 4;
    const int j0 = (tid & 15) * 4;
    #pragma unroll
    for (int i=0;i<4;i++){
        int r = m0 + e0 + i;
        if (r >= M) continue;
        #pragma unroll
        for (int jj=0;jj<4;jj++){
            int c = n0 + j0 + jj;
            float v = acc[i][jj];
            if (MODE == 0) v += bias[c];
            if (MODE == 1){ if (part == 0) v += bias[kblk*256 + (c & 255)]; }
            if (MODE == 2) v += bias[c];
            if (MODE == 0) v = fmaxf(v, 0.f);
            Cf[(size_t)r * Nd + c] = v;
        }
    }
}

// MFMA edge kernel: 64 edges x 256 cols per block, K=768.
// A[e][k] = z_g[e] * relu(ABf[dst][g*512+j] + ABf[src][g*512+256+j]), g=k>>8, j=k&255
// B = W2 [768][256] via pre-transposed bf16 W2T[256][768].
// mfma_f32_16x16x32_bf16; A-frag: m=lane&15, k=quad*8+j; C/D: col=lane&15, row=quad*4+reg.
__global__ __launch_bounds__(256, 2) void edge_mfma(
    const float* __restrict__ ABf, const u16* __restrict__ W2T,
    const float* __restrict__ b2, const float* __restrict__ zf,
    const int* __restrict__ srcA, const int* __restrict__ dstA,
    float* __restrict__ m_acc)
{
    __shared__ __align__(16) u16 Alds[64 * 40];    // row stride 40 u16 (80B): 2-way max aliasing
    __shared__ __align__(16) u16 Blds[256 * 40];   // 20KB
    __shared__ float zc3[3][64];
    __shared__ int dstc[64], srcc[64];
    const int tid = threadIdx.x;
    const int eb = blockIdx.x * 64;

    if (tid < 64){
        srcc[tid] = srcA[eb + tid];
        dstc[tid] = dstA[eb + tid];
    }
    int tz = tid - 64;
    if (tz >= 0 && tz < 192){
        int g = tz / 64, e = tz % 64;
        zc3[g][e] = zf[(size_t)(eb + e) * 4 + 1 + g];
    }
    __syncthreads();

    const int wave = tid >> 6, lane = tid & 63;
    const int quad = lane >> 4, l16 = lane & 15;
    const int est = tid >> 2, seg = tid & 3;

    const f32x4 zero4 = {0.f, 0.f, 0.f, 0.f};
    f32x4 acc[4][4];
    #pragma unroll
    for (int r=0;r<4;r++)
        #pragma unroll
        for (int c=0;c<4;c++) acc[r][c] = zero4;

    const int d = dstc[est], s = srcc[est];

    for (int kc = 0; kc < 768; kc += 32){
        const int g  = kc >> 8;
        const int j0 = (kc & 255) + seg * 8;
        // stage A: gather + relu + z-scale + cvt bf16
        {
            const float4* pa = reinterpret_cast<const float4*>(&ABf[(size_t)d * 1536 + g * 512 + j0]);
            const float4* pb = reinterpret_cast<const float4*>(&ABf[(size_t)s * 1536 + g * 512 + 256 + j0]);
            float4 a0 = pa[0], a1 = pa[1];
            float4 b0 = pb[0], b1 = pb[1];
            float av[8] = {a0.x,a0.y,a0.z,a0.w,a1.x,a1.y,a1.z,a1.w};
            float bv[8] = {b0.x,b0.y,b0.z,b0.w,b1.x,b1.y,b1.z,b1.w};
            float zk = zc3[g][est];
            u16 pk[8];
            #pragma unroll
            for (int i=0;i<8;i++){
                float v = zk * fmaxf(av[i] + bv[i], 0.f);
                pk[i] = f2bf(v);
            }
            *reinterpret_cast<uint4*>(&Alds[est * 40 + seg * 8]) = *reinterpret_cast<uint4*>(pk);
        }
        // stage B: rows n of W2T, k-chunk kc..kc+31
        #pragma unroll
        for (int i=0;i<4;i++){
            int n = (tid >> 2) + i * 64;
            uint4 w = *reinterpret_cast<const uint4*>(&W2T[(size_t)n * 768 + kc + seg * 8]);
            *reinterpret_cast<uint4*>(&Blds[n * 40 + seg * 8]) = w;
        }
        __syncthreads();
        bf16x8 af[4], bfr[4];
        #pragma unroll
        for (int r=0;r<4;r++)
            af[r] = *reinterpret_cast<const bf16x8*>(&Alds[(r*16 + l16) * 40 + quad * 8]);
        #pragma unroll
        for (int c=0;c<4;c++)
            bfr[c] = *reinterpret_cast<const bf16x8*>(&Blds[(wave*64 + c*16 + l16) * 40 + quad * 8]);
        #pragma unroll
        for (int r=0;r<4;r++)
            #pragma unroll
            for (int c=0;c<4;c++)
                acc[r][c] = __builtin_amdgcn_mfma_f32_16x16x32_bf16(af[r], bfr[c], acc[r][c], 0, 0, 0);
        __syncthreads();
    }
    // epilogue: + sum_g z_g*b2[g][col], atomic scatter-add
    #pragma unroll
    for (int c=0;c<4;c++){
        int col = wave*64 + c*16 + l16;
        float b20 = b2[col], b21 = b2[256 + col], b22 = b2[512 + col];
        #pragma unroll
        for (int r=0;r<4;r++){
            #pragma unroll
            for (int reg=0;reg<4;reg++){
                int e = r*16 + quad*4 + reg;
                float v = acc[r][c][reg] + zc3[0][e]*b20 + zc3[1][e]*b21 + zc3[2][e]*b22;
                atomicAdd(&m_acc[(size_t)dstc[e] * 256 + col], v);
            }
        }
    }
}

// GRU gates
__global__ void gates_k(
    const float* __restrict__ gh, const float* __restrict__ m_acc,
    const float* __restrict__ inv_cnt, const float* __restrict__ x,
    const float* __restrict__ prev, const float* __restrict__ Wih,
    const float* __restrict__ bih, float* __restrict__ h, int t)
{
    int idx = blockIdx.x * 256 + threadIdx.x;
    if (idx >= NN * HID) return;
    int n = idx >> 8, j = idx & 255;
    float inp[6];
    if (t < TTEACH){
        #pragma unroll
        for (int c=0;c<6;c++) inp[c] = x[(size_t)n * NFEAT + t * 6 + c];
    } else {
        #pragma unroll
        for (int c=0;c<6;c++) inp[c] = prev[n * 6 + c];
    }
    float m = m_acc[idx] * inv_cnt[n];
    float gxr = bih[j], gxz = bih[256 + j], gxn = bih[512 + j];
    #pragma unroll
    for (int c=0;c<6;c++){
        gxr += inp[c] * Wih[j * 6 + c];
        gxz += inp[c] * Wih[(256 + j) * 6 + c];
        gxn += inp[c] * Wih[(512 + j) * 6 + c];
    }
    float ghr = gh[(size_t)n * 768 + j];
    float ghz = gh[(size_t)n * 768 + 256 + j];
    float ghn = gh[(size_t)n * 768 + 512 + j];
    float r  = 1.f / (1.f + __expf(-(gxr + ghr)));
    float zg = 1.f / (1.f + __expf(-(gxz + ghz)));
    float nn = tanhf(gxn + r * ghn);
    h[idx] = (1.f - zg) * nn + zg * m;
}

// mu = inputs + relu(h @ Wo + bo)
__global__ void mu_k(
    const float* __restrict__ h, const float* __restrict__ Wo,
    const float* __restrict__ bo, const float* __restrict__ x,
    float* __restrict__ prev, void* __restrict__ out,
    const int* __restrict__ flag, int t)
{
    int idx = blockIdx.x * 256 + threadIdx.x;
    if (idx >= NN * 6) return;
    int n = idx / 6, c = idx % 6;
    float acc = bo[c];
    const float* hr = &h[(size_t)n * 256];
    #pragma unroll 8
    for (int j = 0; j < 256; j++) acc += hr[j] * Wo[j * 6 + c];
    float inp;
    if (t < TTEACH) inp = x[(size_t)n * NFEAT + t * 6 + c];
    else            inp = prev[idx];
    float mu = inp + fmaxf(acc, 0.f);
    if (*flag) ((float*)out)[(size_t)n * NFEAT + t * 6 + c] = mu;
    else       ((u16*)out)[(size_t)n * NFEAT + t * 6 + c] = f2bf(mu);
    prev[idx] = mu;
}

extern "C" void kernel_launch(void* const* d_in, const int* in_sizes, int n_in,
                              void* d_out, int out_size, void* d_ws, size_t ws_size,
                              hipStream_t stream)
{
    const void* x_r   = d_in[0];
    const int*  ei    = (const int*)d_in[1];
    const void* z_r   = d_in[2];
    const void* Wf_r  = d_in[3];
    const void* bf_r  = d_in[4];
    const void* W1_r  = d_in[5];
    const void* b1_r  = d_in[6];
    const void* W2_r  = d_in[7];
    const void* b2_r  = d_in[8];
    const void* Wih_r = d_in[9];
    const void* bih_r = d_in[10];
    const void* Whh_r = d_in[11];
    const void* bhh_r = d_in[12];
    const void* Wo_r  = d_in[13];
    const void* bo_r  = d_in[14];

    char* ws = (char*)d_ws;
    size_t off = 0;
    auto alloc = [&](size_t bytes){
        void* p = ws + off;
        off += (bytes + 255) & ~(size_t)255;
        return p;
    };
    float* h     = (float*)alloc((size_t)NN * HID * 4);
    float* prev  = (float*)alloc((size_t)NN * 6 * 4);
    float* fh    = (float*)alloc((size_t)NN * NFEAT * 4);
    float* ABf   = (float*)alloc((size_t)NN * 1536 * 4);
    float* m_acc = (float*)alloc((size_t)NN * HID * 4);
    float* gh    = (float*)alloc((size_t)NN * 768 * 4);
    float* invc  = (float*)alloc((size_t)NN * 4);
    int*   cnt   = (int*)  alloc((size_t)NN * 4);
    float* WhhT  = (float*)alloc((size_t)768 * 256 * 4);
    u16*   W2T   = (u16*)  alloc((size_t)256 * 768 * 2);
    int*   src32 = (int*)  alloc((size_t)NE * 4);
    int*   dst32 = (int*)  alloc((size_t)NE * 4);
    int*   fdt   = (int*)  alloc(256);
    int*   fidx  = (int*)  alloc(256);
    float* xc   = (float*)alloc((size_t)NN * NFEAT * 4);
    float* zc   = (float*)alloc((size_t)NE * 4 * 4);
    float* Wfc  = (float*)alloc((size_t)256 * 192 * 4);
    float* bfc  = (float*)alloc(192 * 4);
    float* W1c  = (float*)alloc((size_t)3 * 384 * 256 * 4);
    float* b1c  = (float*)alloc(768 * 4);
    float* W2c  = (float*)alloc((size_t)3 * 256 * 256 * 4);
    float* b2c  = (float*)alloc(768 * 4);
    float* Wihc = (float*)alloc((size_t)768 * 6 * 4);
    float* bihc = (float*)alloc(768 * 4);
    float* Whhc = (float*)alloc((size_t)768 * 256 * 4);
    float* bhhc = (float*)alloc(768 * 4);
    float* Woc  = (float*)alloc((size_t)256 * 6 * 4);
    float* boc  = (float*)alloc(6 * 4);

    detect_f32<<<1, 1, 0, stream>>>((const u16*)z_r, fdt);
    detect_i64<<<1, 1, 0, stream>>>(ei, fidx);
    copy_edges<<<(NE + 255)/256, 256, 0, stream>>>(ei, fidx, src32, dst32);

    auto conv = [&](const void* in, float* outp, int n){
        conv_f32<<<(n + 255)/256, 256, 0, stream>>>(in, outp, n, fdt);
    };
    conv(x_r,   xc,   NN * NFEAT);
    conv(z_r,   zc,   NE * 4);
    conv(Wf_r,  Wfc,  256 * 192);
    conv(bf_r,  bfc,  192);
    conv(W1_r,  W1c,  3 * 384 * 256);
    conv(b1_r,  b1c,  768);
    conv(W2_r,  W2c,  3 * 256 * 256);
    conv(b2_r,  b2c,  768);
    conv(Wih_r, Wihc, 768 * 6);
    conv(bih_r, bihc, 768);
    conv(Whh_r, Whhc, 768 * 256);
    conv(bhh_r, bhhc, 768);
    conv(Wo_r,  Woc,  256 * 6);
    conv(bo_r,  boc,  6);

    fill_f32<<<(NN*HID + 255)/256, 256, 0, stream>>>(h, 0.f, NN*HID);
    fill_f32<<<(NN*6 + 255)/256, 256, 0, stream>>>(prev, 0.f, NN*6);
    fill_i32<<<(NN + 255)/256, 256, 0, stream>>>(cnt, 0, NN);
    degree_k<<<(NE + 255)/256, 256, 0, stream>>>(dst32, cnt, NE);
    invcnt_k<<<(NN + 255)/256, 256, 0, stream>>>(cnt, invc, NN);
    transpose_whh<<<(768*256 + 255)/256, 256, 0, stream>>>(Whhc, WhhT);
    build_w2t<<<(768*256 + 255)/256, 256, 0, stream>>>(W2c, W2T);

    for (int t = 0; t < TS; t++){
        gemm64<0><<<dim3(157, 3), 256, 0, stream>>>(h, Wfc, bfc, fh, nullptr, NN, 256, NFEAT);
        gemm64<1><<<dim3(157, 24), 256, 0, stream>>>(fh, W1c, b1c, ABf, nullptr, NN, NFEAT, 1536);
        fill_f32<<<(NN*HID + 255)/256, 256, 0, stream>>>(m_acc, 0.f, NN*HID);
        edge_mfma<<<2500, 256, 0, stream>>>(ABf, W2T, b2c, zc, src32, dst32, m_acc);
        gemm64<2><<<dim3(157, 12), 256, 0, stream>>>(m_acc, WhhT, bhhc, gh, invc, NN, 256, 768);
        gates_k<<<(NN*HID + 255)/256, 256, 0, stream>>>(gh, m_acc, invc, xc, prev, Wihc, bihc, h, t);
        mu_k<<<(NN*6 + 255)/256, 256, 0, stream>>>(h, Woc, boc, xc, prev, d_out, fdt, t);
    }
}

// Round 6
// 9832.272 us; speedup vs baseline: 4.7256x; 1.3122x over previous
//
#include <hip/hip_runtime.h>
#include <hip/hip_bf16.h>

#define NN 10000      // nodes
#define NE 160000     // edges
#define TS 32         // timesteps
#define HID 256
#define NFEAT 192
#define TTEACH 24

typedef unsigned short u16;
typedef unsigned int u32;
typedef __attribute__((ext_vector_type(8))) short bf16x8;
typedef __attribute__((ext_vector_type(4))) float f32x4;

__device__ __forceinline__ float bf2f(u16 u){
    u32 v = ((u32)u) << 16;
    union { u32 i; float f; } c; c.i = v; return c.f;
}
__device__ __forceinline__ u16 f2bf(float f){
    union { float f; u32 i; } c; c.f = f;
    u32 i = c.i;
    u32 lsb = (i >> 16) & 1u;
    i += 0x7fffu + lsb;
    return (u16)(i >> 16);
}

__global__ void fill_f32(float* p, float v, int n){
    int i = blockIdx.x * 256 + threadIdx.x;
    if (i < n) p[i] = v;
}
__global__ void fill_i32(int* p, int v, int n){
    int i = blockIdx.x * 256 + threadIdx.x;
    if (i < n) p[i] = v;
}

// ---------- runtime dtype detection ----------
__global__ void detect_f32(const u16* __restrict__ zraw, int* __restrict__ flag){
    int c = 0;
    for (int i = 0; i < 128; i++) if (zraw[2*i] >= 0x4000) c++;
    *flag = (c > 8) ? 1 : 0;
}
__global__ void conv_f32(const void* __restrict__ in, float* __restrict__ outp,
                         int n, const int* __restrict__ flag){
    int i = blockIdx.x * 256 + threadIdx.x;
    if (i >= n) return;
    if (*flag) outp[i] = ((const float*)in)[i];
    else       outp[i] = bf2f(((const u16*)in)[i]);
}
__global__ void detect_i64(const int* __restrict__ ei_raw, int* __restrict__ flag){
    int zz = 0;
    #pragma unroll
    for (int i = 0; i < 32; i++) zz |= ei_raw[2*i + 1];
    *flag = (zz == 0) ? 1 : 0;
}
__global__ void copy_edges(const int* __restrict__ ei_raw, const int* __restrict__ flag,
                           int* __restrict__ src, int* __restrict__ dst){
    int e = blockIdx.x * 256 + threadIdx.x;
    if (e >= NE) return;
    int st = (*flag) ? 2 : 1;
    src[e] = ei_raw[(size_t)e * st];
    dst[e] = ei_raw[((size_t)NE + e) * st];
}

__global__ void degree_k(const int* __restrict__ dst, int* __restrict__ cnt, int n){
    int e = blockIdx.x * 256 + threadIdx.x;
    if (e < n) atomicAdd(&cnt[dst[e]], 1);
}
__global__ void invcnt_k(const int* __restrict__ cnt, float* __restrict__ inv, int n){
    int i = blockIdx.x * 256 + threadIdx.x;
    if (i < n) inv[i] = 1.0f / fmaxf((float)cnt[i], 1.0f);
}
// WfT[n][k] = Wf[k][n] bf16  (Wf: [256][192])
__global__ void build_wft(const float* __restrict__ Wfc, u16* __restrict__ WfT){
    int idx = blockIdx.x * 256 + threadIdx.x;
    if (idx < 256 * 192){
        int k = idx / 192, n = idx % 192;
        WfT[(size_t)n * 256 + k] = f2bf(Wfc[idx]);
    }
}
// W1T[n][k] bf16, n in [0,1536): kblk=n>>9, part=(n>>8)&1, c=n&255; k in [0,192)
__global__ void build_w1t(const float* __restrict__ W1c, u16* __restrict__ W1T){
    int idx = blockIdx.x * 256 + threadIdx.x;
    if (idx < 1536 * 192){
        int n = idx / 192, k = idx % 192;
        int kblk = n >> 9, part = (n >> 8) & 1, c = n & 255;
        W1T[idx] = f2bf(W1c[(size_t)kblk * (384*256) + (size_t)(part*192 + k) * 256 + c]);
    }
}
// bf16 cast (Whh is already B-layout for gh = m @ Whh^T)
__global__ void conv_bf16(const float* __restrict__ in, u16* __restrict__ outp, int n){
    int i = blockIdx.x * 256 + threadIdx.x;
    if (i < n) outp[i] = f2bf(in[i]);
}
// W2T[n][k] = W2[k][n] bf16; W2 flat [768][256] fp32
__global__ void build_w2t(const float* __restrict__ W2c, u16* __restrict__ W2T){
    int idx = blockIdx.x * 256 + threadIdx.x;
    if (idx < 768 * 256){
        int k = idx / 256, n = idx % 256;
        W2T[(size_t)n * 768 + k] = f2bf(W2c[idx]);
    }
}
// m16[n][j] = bf16(m_acc[n][j] * inv[n])
__global__ void mscale_k(const float* __restrict__ m_acc, const float* __restrict__ inv,
                         u16* __restrict__ m16){
    int idx = blockIdx.x * 256 + threadIdx.x;
    if (idx < NN * HID) m16[idx] = f2bf(m_acc[idx] * inv[idx >> 8]);
}

// ---------------- MFMA node GEMM ----------------
// C[M,N] = epi(A16[M,K] @ BT16[N,K]^T + bias)
// Block: 4 waves; tile 256 rows x 64 cols; wave w owns rows w*64..w*64+63.
// MODE 0: +bias, relu, out bf16 (fh16)
// MODE 1: +b1 if part==0 (W1 packing), out bf16 (AB16)
// MODE 2: +bias, out fp32 (gh)
template<int MODE>
__global__ __launch_bounds__(256, 2) void gemm_mfma(
    const u16* __restrict__ A16, const u16* __restrict__ BT16,
    const float* __restrict__ bias, float* __restrict__ Cf, u16* __restrict__ Cb,
    int M, int Kd, int Nd)
{
    __shared__ __align__(16) u16 Alds[256 * 40];  // 20KB, stride 40 -> 2-way max aliasing
    __shared__ __align__(16) u16 Blds[64 * 40];   // 5KB
    const int tid = threadIdx.x;
    const int m0 = blockIdx.x * 256;
    const int n0 = blockIdx.y * 64;
    const int wave = tid >> 6, lane = tid & 63;
    const int quad = lane >> 4, l16 = lane & 15;

    const f32x4 zero4 = {0.f, 0.f, 0.f, 0.f};
    f32x4 acc[4][4];
    #pragma unroll
    for (int r=0;r<4;r++)
        #pragma unroll
        for (int c=0;c<4;c++) acc[r][c] = zero4;

    const int arow = m0 + tid;
    const u16* ap = &A16[(size_t)arow * Kd];
    const int bn = tid >> 2, bseg = tid & 3;
    const u16* bp = &BT16[(size_t)(n0 + bn) * Kd + bseg * 8];

    for (int k0 = 0; k0 < Kd; k0 += 32){
        // stage A: 256 rows x 32 k, one row per thread
        if (arow < M){
            const uint4* q = reinterpret_cast<const uint4*>(ap + k0);
            uint4 v0 = q[0], v1 = q[1], v2 = q[2], v3 = q[3];
            *reinterpret_cast<uint4*>(&Alds[tid * 40])      = v0;
            *reinterpret_cast<uint4*>(&Alds[tid * 40 + 8])  = v1;
            *reinterpret_cast<uint4*>(&Alds[tid * 40 + 16]) = v2;
            *reinterpret_cast<uint4*>(&Alds[tid * 40 + 24]) = v3;
        } else {
            uint4 zz = {0,0,0,0};
            #pragma unroll
            for (int s=0;s<4;s++)
                *reinterpret_cast<uint4*>(&Alds[tid * 40 + s*8]) = zz;
        }
        // stage B: 64 cols x 32 k
        {
            uint4 v = *reinterpret_cast<const uint4*>(bp + k0);
            *reinterpret_cast<uint4*>(&Blds[bn * 40 + bseg * 8]) = v;
        }
        __syncthreads();
        bf16x8 af[4], bfr[4];
        #pragma unroll
        for (int r=0;r<4;r++)
            af[r] = *reinterpret_cast<const bf16x8*>(&Alds[(wave*64 + r*16 + l16) * 40 + quad * 8]);
        #pragma unroll
        for (int c=0;c<4;c++)
            bfr[c] = *reinterpret_cast<const bf16x8*>(&Blds[(c*16 + l16) * 40 + quad * 8]);
        #pragma unroll
        for (int r=0;r<4;r++)
            #pragma unroll
            for (int c=0;c<4;c++)
                acc[r][c] = __builtin_amdgcn_mfma_f32_16x16x32_bf16(af[r], bfr[c], acc[r][c], 0, 0, 0);
        __syncthreads();
    }
    // epilogue: C/D layout col=lane&15, row=quad*4+reg
    #pragma unroll
    for (int c=0;c<4;c++){
        int col = n0 + c*16 + l16;
        float bv = 0.f;
        if (MODE == 0 || MODE == 2) bv = bias[col];
        if (MODE == 1){
            int part = (col >> 8) & 1;
            if (part == 0) bv = bias[(col >> 9) * 256 + (col & 255)];
        }
        #pragma unroll
        for (int r=0;r<4;r++){
            #pragma unroll
            for (int reg=0;reg<4;reg++){
                int row = m0 + wave*64 + r*16 + quad*4 + reg;
                if (row >= M) continue;
                float v = acc[r][c][reg] + bv;
                if (MODE == 0) v = fmaxf(v, 0.f);
                if (MODE == 2) Cf[(size_t)row * Nd + col] = v;
                else           Cb[(size_t)row * Nd + col] = f2bf(v);
            }
        }
    }
}

// MFMA edge kernel: 64 edges x 256 cols per block, K=768. AB16 is bf16.
__global__ __launch_bounds__(256, 2) void edge_mfma(
    const u16* __restrict__ AB16, const u16* __restrict__ W2T,
    const float* __restrict__ b2, const float* __restrict__ zf,
    const int* __restrict__ srcA, const int* __restrict__ dstA,
    float* __restrict__ m_acc)
{
    __shared__ __align__(16) u16 Alds[64 * 40];
    __shared__ __align__(16) u16 Blds[256 * 40];
    __shared__ float zc3[3][64];
    __shared__ int dstc[64], srcc[64];
    const int tid = threadIdx.x;
    const int eb = blockIdx.x * 64;

    if (tid < 64){
        srcc[tid] = srcA[eb + tid];
        dstc[tid] = dstA[eb + tid];
    }
    int tz = tid - 64;
    if (tz >= 0 && tz < 192){
        int g = tz / 64, e = tz % 64;
        zc3[g][e] = zf[(size_t)(eb + e) * 4 + 1 + g];
    }
    __syncthreads();

    const int wave = tid >> 6, lane = tid & 63;
    const int quad = lane >> 4, l16 = lane & 15;
    const int est = tid >> 2, seg = tid & 3;

    const f32x4 zero4 = {0.f, 0.f, 0.f, 0.f};
    f32x4 acc[4][4];
    #pragma unroll
    for (int r=0;r<4;r++)
        #pragma unroll
        for (int c=0;c<4;c++) acc[r][c] = zero4;

    const int d = dstc[est], s = srcc[est];

    for (int kc = 0; kc < 768; kc += 32){
        const int g  = kc >> 8;
        const int j0 = (kc & 255) + seg * 8;
        // stage A: gather bf16 + relu + z-scale + repack bf16
        {
            uint4 ua = *reinterpret_cast<const uint4*>(&AB16[(size_t)d * 1536 + g * 512 + j0]);
            uint4 ub = *reinterpret_cast<const uint4*>(&AB16[(size_t)s * 1536 + g * 512 + 256 + j0]);
            const u16* wa = (const u16*)&ua;
            const u16* wb = (const u16*)&ub;
            float zk = zc3[g][est];
            u16 pk[8];
            #pragma unroll
            for (int i=0;i<8;i++){
                float v = zk * fmaxf(bf2f(wa[i]) + bf2f(wb[i]), 0.f);
                pk[i] = f2bf(v);
            }
            *reinterpret_cast<uint4*>(&Alds[est * 40 + seg * 8]) = *reinterpret_cast<uint4*>(pk);
        }
        // stage B
        #pragma unroll
        for (int i=0;i<4;i++){
            int n = (tid >> 2) + i * 64;
            uint4 w = *reinterpret_cast<const uint4*>(&W2T[(size_t)n * 768 + kc + seg * 8]);
            *reinterpret_cast<uint4*>(&Blds[n * 40 + seg * 8]) = w;
        }
        __syncthreads();
        bf16x8 af[4], bfr[4];
        #pragma unroll
        for (int r=0;r<4;r++)
            af[r] = *reinterpret_cast<const bf16x8*>(&Alds[(r*16 + l16) * 40 + quad * 8]);
        #pragma unroll
        for (int c=0;c<4;c++)
            bfr[c] = *reinterpret_cast<const bf16x8*>(&Blds[(wave*64 + c*16 + l16) * 40 + quad * 8]);
        #pragma unroll
        for (int r=0;r<4;r++)
            #pragma unroll
            for (int c=0;c<4;c++)
                acc[r][c] = __builtin_amdgcn_mfma_f32_16x16x32_bf16(af[r], bfr[c], acc[r][c], 0, 0, 0);
        __syncthreads();
    }
    // epilogue: + sum_g z_g*b2[g][col], atomic scatter-add
    #pragma unroll
    for (int c=0;c<4;c++){
        int col = wave*64 + c*16 + l16;
        float b20 = b2[col], b21 = b2[256 + col], b22 = b2[512 + col];
        #pragma unroll
        for (int r=0;r<4;r++){
            #pragma unroll
            for (int reg=0;reg<4;reg++){
                int e = r*16 + quad*4 + reg;
                float v = acc[r][c][reg] + zc3[0][e]*b20 + zc3[1][e]*b21 + zc3[2][e]*b22;
                atomicAdd(&m_acc[(size_t)dstc[e] * 256 + col], v);
            }
        }
    }
}

// GRU gates; also writes h16 (bf16 copy for next step's GEMM-0)
__global__ void gates_k(
    const float* __restrict__ gh, const float* __restrict__ m_acc,
    const float* __restrict__ inv_cnt, const float* __restrict__ x,
    const float* __restrict__ prev, const float* __restrict__ Wih,
    const float* __restrict__ bih, float* __restrict__ h,
    u16* __restrict__ h16, int t)
{
    int idx = blockIdx.x * 256 + threadIdx.x;
    if (idx >= NN * HID) return;
    int n = idx >> 8, j = idx & 255;
    float inp[6];
    if (t < TTEACH){
        #pragma unroll
        for (int c=0;c<6;c++) inp[c] = x[(size_t)n * NFEAT + t * 6 + c];
    } else {
        #pragma unroll
        for (int c=0;c<6;c++) inp[c] = prev[n * 6 + c];
    }
    float m = m_acc[idx] * inv_cnt[n];
    float gxr = bih[j], gxz = bih[256 + j], gxn = bih[512 + j];
    #pragma unroll
    for (int c=0;c<6;c++){
        gxr += inp[c] * Wih[j * 6 + c];
        gxz += inp[c] * Wih[(256 + j) * 6 + c];
        gxn += inp[c] * Wih[(512 + j) * 6 + c];
    }
    float ghr = gh[(size_t)n * 768 + j];
    float ghz = gh[(size_t)n * 768 + 256 + j];
    float ghn = gh[(size_t)n * 768 + 512 + j];
    float r  = 1.f / (1.f + __expf(-(gxr + ghr)));
    float zg = 1.f / (1.f + __expf(-(gxz + ghz)));
    float nn = tanhf(gxn + r * ghn);
    float hv = (1.f - zg) * nn + zg * m;
    h[idx] = hv;
    h16[idx] = f2bf(hv);
}

// mu = inputs + relu(h @ Wo + bo)
__global__ void mu_k(
    const float* __restrict__ h, const float* __restrict__ Wo,
    const float* __restrict__ bo, const float* __restrict__ x,
    float* __restrict__ prev, void* __restrict__ out,
    const int* __restrict__ flag, int t)
{
    int idx = blockIdx.x * 256 + threadIdx.x;
    if (idx >= NN * 6) return;
    int n = idx / 6, c = idx % 6;
    float acc = bo[c];
    const float* hr = &h[(size_t)n * 256];
    #pragma unroll 8
    for (int j = 0; j < 256; j++) acc += hr[j] * Wo[j * 6 + c];
    float inp;
    if (t < TTEACH) inp = x[(size_t)n * NFEAT + t * 6 + c];
    else            inp = prev[idx];
    float mu = inp + fmaxf(acc, 0.f);
    if (*flag) ((float*)out)[(size_t)n * NFEAT + t * 6 + c] = mu;
    else       ((u16*)out)[(size_t)n * NFEAT + t * 6 + c] = f2bf(mu);
    prev[idx] = mu;
}

extern "C" void kernel_launch(void* const* d_in, const int* in_sizes, int n_in,
                              void* d_out, int out_size, void* d_ws, size_t ws_size,
                              hipStream_t stream)
{
    const void* x_r   = d_in[0];
    const int*  ei    = (const int*)d_in[1];
    const void* z_r   = d_in[2];
    const void* Wf_r  = d_in[3];
    const void* bf_r  = d_in[4];
    const void* W1_r  = d_in[5];
    const void* b1_r  = d_in[6];
    const void* W2_r  = d_in[7];
    const void* b2_r  = d_in[8];
    const void* Wih_r = d_in[9];
    const void* bih_r = d_in[10];
    const void* Whh_r = d_in[11];
    const void* bhh_r = d_in[12];
    const void* Wo_r  = d_in[13];
    const void* bo_r  = d_in[14];

    char* ws = (char*)d_ws;
    size_t off = 0;
    auto alloc = [&](size_t bytes){
        void* p = ws + off;
        off += (bytes + 255) & ~(size_t)255;
        return p;
    };
    float* h     = (float*)alloc((size_t)NN * HID * 4);
    u16*   h16   = (u16*)  alloc((size_t)NN * HID * 2);
    float* prev  = (float*)alloc((size_t)NN * 6 * 4);
    u16*   fh16  = (u16*)  alloc((size_t)NN * NFEAT * 2);
    u16*   AB16  = (u16*)  alloc((size_t)NN * 1536 * 2);
    float* m_acc = (float*)alloc((size_t)NN * HID * 4);
    u16*   m16   = (u16*)  alloc((size_t)NN * HID * 2);
    float* gh    = (float*)alloc((size_t)NN * 768 * 4);
    float* invc  = (float*)alloc((size_t)NN * 4);
    int*   cnt   = (int*)  alloc((size_t)NN * 4);
    u16*   WfT   = (u16*)  alloc((size_t)192 * 256 * 2);
    u16*   W1T   = (u16*)  alloc((size_t)1536 * 192 * 2);
    u16*   Whh16 = (u16*)  alloc((size_t)768 * 256 * 2);
    u16*   W2T   = (u16*)  alloc((size_t)256 * 768 * 2);
    int*   src32 = (int*)  alloc((size_t)NE * 4);
    int*   dst32 = (int*)  alloc((size_t)NE * 4);
    int*   fdt   = (int*)  alloc(256);
    int*   fidx  = (int*)  alloc(256);
    float* xc   = (float*)alloc((size_t)NN * NFEAT * 4);
    float* zc   = (float*)alloc((size_t)NE * 4 * 4);
    float* Wfc  = (float*)alloc((size_t)256 * 192 * 4);
    float* bfc  = (float*)alloc(192 * 4);
    float* W1c  = (float*)alloc((size_t)3 * 384 * 256 * 4);
    float* b1c  = (float*)alloc(768 * 4);
    float* W2c  = (float*)alloc((size_t)3 * 256 * 256 * 4);
    float* b2c  = (float*)alloc(768 * 4);
    float* Wihc = (float*)alloc((size_t)768 * 6 * 4);
    float* bihc = (float*)alloc(768 * 4);
    float* Whhc = (float*)alloc((size_t)768 * 256 * 4);
    float* bhhc = (float*)alloc(768 * 4);
    float* Woc  = (float*)alloc((size_t)256 * 6 * 4);
    float* boc  = (float*)alloc(6 * 4);

    detect_f32<<<1, 1, 0, stream>>>((const u16*)z_r, fdt);
    detect_i64<<<1, 1, 0, stream>>>(ei, fidx);
    copy_edges<<<(NE + 255)/256, 256, 0, stream>>>(ei, fidx, src32, dst32);

    auto conv = [&](const void* in, float* outp, int n){
        conv_f32<<<(n + 255)/256, 256, 0, stream>>>(in, outp, n, fdt);
    };
    conv(x_r,   xc,   NN * NFEAT);
    conv(z_r,   zc,   NE * 4);
    conv(Wf_r,  Wfc,  256 * 192);
    conv(bf_r,  bfc,  192);
    conv(W1_r,  W1c,  3 * 384 * 256);
    conv(b1_r,  b1c,  768);
    conv(W2_r,  W2c,  3 * 256 * 256);
    conv(b2_r,  b2c,  768);
    conv(Wih_r, Wihc, 768 * 6);
    conv(bih_r, bihc, 768);
    conv(Whh_r, Whhc, 768 * 256);
    conv(bhh_r, bhhc, 768);
    conv(Wo_r,  Woc,  256 * 6);
    conv(bo_r,  boc,  6);

    fill_f32<<<(NN*HID + 255)/256, 256, 0, stream>>>(h, 0.f, NN*HID);
    fill_f32<<<(NN*HID/2 + 255)/256, 256, 0, stream>>>((float*)h16, 0.f, NN*HID/2);
    fill_f32<<<(NN*6 + 255)/256, 256, 0, stream>>>(prev, 0.f, NN*6);
    fill_i32<<<(NN + 255)/256, 256, 0, stream>>>(cnt, 0, NN);
    degree_k<<<(NE + 255)/256, 256, 0, stream>>>(dst32, cnt, NE);
    invcnt_k<<<(NN + 255)/256, 256, 0, stream>>>(cnt, invc, NN);
    build_wft<<<(256*192 + 255)/256, 256, 0, stream>>>(Wfc, WfT);
    build_w1t<<<(1536*192 + 255)/256, 256, 0, stream>>>(W1c, W1T);
    conv_bf16<<<(768*256 + 255)/256, 256, 0, stream>>>(Whhc, Whh16, 768*256);
    build_w2t<<<(768*256 + 255)/256, 256, 0, stream>>>(W2c, W2T);

    for (int t = 0; t < TS; t++){
        // fh16 = relu(h16 @ WfT^T + bf)      [10000,256]x[256,192] MFMA
        gemm_mfma<0><<<dim3(40, 3), 256, 0, stream>>>(h16, WfT, bfc, nullptr, fh16, NN, 256, NFEAT);
        // AB16 = fh16 @ W1T^T (+b1 A-part)   [10000,192]x[192,1536] MFMA
        gemm_mfma<1><<<dim3(40, 24), 256, 0, stream>>>(fh16, W1T, b1c, nullptr, AB16, NN, NFEAT, 1536);
        fill_f32<<<(NN*HID + 255)/256, 256, 0, stream>>>(m_acc, 0.f, NN*HID);
        edge_mfma<<<2500, 256, 0, stream>>>(AB16, W2T, b2c, zc, src32, dst32, m_acc);
        mscale_k<<<(NN*HID + 255)/256, 256, 0, stream>>>(m_acc, invc, m16);
        // gh = m16 @ Whh16^T + bhh           [10000,256]x[256,768] MFMA, fp32 out
        gemm_mfma<2><<<dim3(40, 12), 256, 0, stream>>>(m16, Whh16, bhhc, gh, nullptr, NN, 256, 768);
        gates_k<<<(NN*HID + 255)/256, 256, 0, stream>>>(gh, m_acc, invc, xc, prev, Wihc, bihc, h, h16, t);
        mu_k<<<(NN*6 + 255)/256, 256, 0, stream>>>(h, Woc, boc, xc, prev, d_out, fdt, t);
    }
}

// Round 7
// 8076.736 us; speedup vs baseline: 5.7527x; 1.2174x over previous
//
#include <hip/hip_runtime.h>
#include <hip/hip_bf16.h>

#define NN 10000      // nodes
#define NE 160000     // edges
#define TS 32         // timesteps
#define HID 256
#define NFEAT 192
#define TTEACH 24

typedef unsigned short u16;
typedef unsigned int u32;
typedef __attribute__((ext_vector_type(8))) short bf16x8;
typedef __attribute__((ext_vector_type(4))) float f32x4;

__device__ __forceinline__ float bf2f(u16 u){
    u32 v = ((u32)u) << 16;
    union { u32 i; float f; } c; c.i = v; return c.f;
}
__device__ __forceinline__ u16 f2bf(float f){
    union { float f; u32 i; } c; c.f = f;
    u32 i = c.i;
    u32 lsb = (i >> 16) & 1u;
    i += 0x7fffu + lsb;
    return (u16)(i >> 16);
}

__global__ void fill_f32(float* p, float v, int n){
    int i = blockIdx.x * 256 + threadIdx.x;
    if (i < n) p[i] = v;
}
__global__ void fill_i32(int* p, int v, int n){
    int i = blockIdx.x * 256 + threadIdx.x;
    if (i < n) p[i] = v;
}
__global__ void copy_i32(const int* __restrict__ a, int* __restrict__ b, int n){
    int i = blockIdx.x * 256 + threadIdx.x;
    if (i < n) b[i] = a[i];
}

// ---------- runtime dtype detection ----------
__global__ void detect_f32(const u16* __restrict__ zraw, int* __restrict__ flag){
    int c = 0;
    for (int i = 0; i < 128; i++) if (zraw[2*i] >= 0x4000) c++;
    *flag = (c > 8) ? 1 : 0;
}
__global__ void conv_f32(const void* __restrict__ in, float* __restrict__ outp,
                         int n, const int* __restrict__ flag){
    int i = blockIdx.x * 256 + threadIdx.x;
    if (i >= n) return;
    if (*flag) outp[i] = ((const float*)in)[i];
    else       outp[i] = bf2f(((const u16*)in)[i]);
}
__global__ void detect_i64(const int* __restrict__ ei_raw, int* __restrict__ flag){
    int zz = 0;
    #pragma unroll
    for (int i = 0; i < 32; i++) zz |= ei_raw[2*i + 1];
    *flag = (zz == 0) ? 1 : 0;
}
__global__ void copy_edges(const int* __restrict__ ei_raw, const int* __restrict__ flag,
                           int* __restrict__ src, int* __restrict__ dst){
    int e = blockIdx.x * 256 + threadIdx.x;
    if (e >= NE) return;
    int st = (*flag) ? 2 : 1;
    src[e] = ei_raw[(size_t)e * st];
    dst[e] = ei_raw[((size_t)NE + e) * st];
}

__global__ void degree_k(const int* __restrict__ dst, int* __restrict__ cnt, int n){
    int e = blockIdx.x * 256 + threadIdx.x;
    if (e < n) atomicAdd(&cnt[dst[e]], 1);
}
__global__ void invcnt_k(const int* __restrict__ cnt, float* __restrict__ inv, int n){
    int i = blockIdx.x * 256 + threadIdx.x;
    if (i < n) inv[i] = 1.0f / fmaxf((float)cnt[i], 1.0f);
}

// exclusive scan of cnt[10000] -> binoff[10000], single block 1024 threads
__global__ void scan_k(const int* __restrict__ cnt, int* __restrict__ binoff){
    __shared__ int ps[1024];
    int t = threadIdx.x;
    int s = 0;
    if (t < 1000)
        for (int i = 0; i < 10; i++) s += cnt[t*10 + i];
    ps[t] = s;
    __syncthreads();
    for (int ofs = 1; ofs < 1024; ofs <<= 1){
        int v = (t >= ofs) ? ps[t - ofs] : 0;
        __syncthreads();
        ps[t] += v;
        __syncthreads();
    }
    if (t < 1000){
        int run = (t == 0) ? 0 : ps[t-1];
        for (int i = 0; i < 10; i++){
            binoff[t*10 + i] = run;
            run += cnt[t*10 + i];
        }
    }
}
// scatter edges into dst-sorted order; builds sorted src/dst and z planes
__global__ void scatter_k(const int* __restrict__ src32, const int* __restrict__ dst32,
                          const float* __restrict__ zc, int* __restrict__ cur,
                          int* __restrict__ srcS, int* __restrict__ dstS,
                          float* __restrict__ zS){
    int e = blockIdx.x * 256 + threadIdx.x;
    if (e >= NE) return;
    int d = dst32[e];
    int pos = atomicAdd(&cur[d], 1);
    srcS[pos] = src32[e];
    dstS[pos] = d;
    zS[pos]        = zc[(size_t)e*4 + 1];
    zS[NE + pos]   = zc[(size_t)e*4 + 2];
    zS[2*NE + pos] = zc[(size_t)e*4 + 3];
}

// WfT[n][k] = Wf[k][n] bf16  (Wf: [256][192])
__global__ void build_wft(const float* __restrict__ Wfc, u16* __restrict__ WfT){
    int idx = blockIdx.x * 256 + threadIdx.x;
    if (idx < 256 * 192){
        int k = idx / 192, n = idx % 192;
        WfT[(size_t)n * 256 + k] = f2bf(Wfc[idx]);
    }
}
// W1T[n][k] bf16, n in [0,1536): kblk=n>>9, part=(n>>8)&1, c=n&255; k in [0,192)
__global__ void build_w1t(const float* __restrict__ W1c, u16* __restrict__ W1T){
    int idx = blockIdx.x * 256 + threadIdx.x;
    if (idx < 1536 * 192){
        int n = idx / 192, k = idx % 192;
        int kblk = n >> 9, part = (n >> 8) & 1, c = n & 255;
        W1T[idx] = f2bf(W1c[(size_t)kblk * (384*256) + (size_t)(part*192 + k) * 256 + c]);
    }
}
__global__ void conv_bf16(const float* __restrict__ in, u16* __restrict__ outp, int n){
    int i = blockIdx.x * 256 + threadIdx.x;
    if (i < n) outp[i] = f2bf(in[i]);
}
// W2T[n][k] = W2[k][n] bf16; W2 flat [768][256] fp32
__global__ void build_w2t(const float* __restrict__ W2c, u16* __restrict__ W2T){
    int idx = blockIdx.x * 256 + threadIdx.x;
    if (idx < 768 * 256){
        int k = idx / 256, n = idx % 256;
        W2T[(size_t)n * 768 + k] = f2bf(W2c[idx]);
    }
}
// m16 = bf16(m_acc * inv); also re-zeros m_acc for the next step's atomics
__global__ void mscale_k(float* __restrict__ m_acc, const float* __restrict__ inv,
                         u16* __restrict__ m16){
    int idx = blockIdx.x * 256 + threadIdx.x;
    if (idx < NN * HID){
        m16[idx] = f2bf(m_acc[idx] * inv[idx >> 8]);
        m_acc[idx] = 0.f;
    }
}

// ---------------- MFMA node GEMM ----------------
// C[M,N] = epi(A16[M,K] @ BT16[N,K]^T + bias)
// MODE 0: +bias, relu, out bf16 | MODE 1: +b1 if part==0, out bf16 | MODE 2: +bias, out fp32
template<int MODE>
__global__ __launch_bounds__(256, 2) void gemm_mfma(
    const u16* __restrict__ A16, const u16* __restrict__ BT16,
    const float* __restrict__ bias, float* __restrict__ Cf, u16* __restrict__ Cb,
    int M, int Kd, int Nd)
{
    __shared__ __align__(16) u16 Alds[256 * 40];
    __shared__ __align__(16) u16 Blds[64 * 40];
    const int tid = threadIdx.x;
    const int m0 = blockIdx.x * 256;
    const int n0 = blockIdx.y * 64;
    const int wave = tid >> 6, lane = tid & 63;
    const int quad = lane >> 4, l16 = lane & 15;

    const f32x4 zero4 = {0.f, 0.f, 0.f, 0.f};
    f32x4 acc[4][4];
    #pragma unroll
    for (int r=0;r<4;r++)
        #pragma unroll
        for (int c=0;c<4;c++) acc[r][c] = zero4;

    const int arow = m0 + tid;
    const u16* ap = &A16[(size_t)arow * Kd];
    const int bn = tid >> 2, bseg = tid & 3;
    const u16* bp = &BT16[(size_t)(n0 + bn) * Kd + bseg * 8];

    for (int k0 = 0; k0 < Kd; k0 += 32){
        if (arow < M){
            const uint4* q = reinterpret_cast<const uint4*>(ap + k0);
            uint4 v0 = q[0], v1 = q[1], v2 = q[2], v3 = q[3];
            *reinterpret_cast<uint4*>(&Alds[tid * 40])      = v0;
            *reinterpret_cast<uint4*>(&Alds[tid * 40 + 8])  = v1;
            *reinterpret_cast<uint4*>(&Alds[tid * 40 + 16]) = v2;
            *reinterpret_cast<uint4*>(&Alds[tid * 40 + 24]) = v3;
        } else {
            uint4 zz = {0,0,0,0};
            #pragma unroll
            for (int s=0;s<4;s++)
                *reinterpret_cast<uint4*>(&Alds[tid * 40 + s*8]) = zz;
        }
        {
            uint4 v = *reinterpret_cast<const uint4*>(bp + k0);
            *reinterpret_cast<uint4*>(&Blds[bn * 40 + bseg * 8]) = v;
        }
        __syncthreads();
        bf16x8 af[4], bfr[4];
        #pragma unroll
        for (int r=0;r<4;r++)
            af[r] = *reinterpret_cast<const bf16x8*>(&Alds[(wave*64 + r*16 + l16) * 40 + quad * 8]);
        #pragma unroll
        for (int c=0;c<4;c++)
            bfr[c] = *reinterpret_cast<const bf16x8*>(&Blds[(c*16 + l16) * 40 + quad * 8]);
        #pragma unroll
        for (int r=0;r<4;r++)
            #pragma unroll
            for (int c=0;c<4;c++)
                acc[r][c] = __builtin_amdgcn_mfma_f32_16x16x32_bf16(af[r], bfr[c], acc[r][c], 0, 0, 0);
        __syncthreads();
    }
    #pragma unroll
    for (int c=0;c<4;c++){
        int col = n0 + c*16 + l16;
        float bv = 0.f;
        if (MODE == 0 || MODE == 2) bv = bias[col];
        if (MODE == 1){
            int part = (col >> 8) & 1;
            if (part == 0) bv = bias[(col >> 9) * 256 + (col & 255)];
        }
        #pragma unroll
        for (int r=0;r<4;r++){
            #pragma unroll
            for (int reg=0;reg<4;reg++){
                int row = m0 + wave*64 + r*16 + quad*4 + reg;
                if (row >= M) continue;
                float v = acc[r][c][reg] + bv;
                if (MODE == 0) v = fmaxf(v, 0.f);
                if (MODE == 2) Cf[(size_t)row * Nd + col] = v;
                else           Cb[(size_t)row * Nd + col] = f2bf(v);
            }
        }
    }
}

// MFMA edge kernel on dst-sorted edges: 64 edges x 256 cols per block, K=768.
// Epilogue: segment-reduce along sorted dst runs, one atomicAdd per (run, col).
__global__ __launch_bounds__(256, 2) void edge_mfma(
    const u16* __restrict__ AB16, const u16* __restrict__ W2T,
    const float* __restrict__ b2, const float* __restrict__ zS,
    const int* __restrict__ srcS, const int* __restrict__ dstS,
    float* __restrict__ m_acc)
{
    __shared__ __align__(16) u16 Alds[64 * 40];     // 5 KB
    __shared__ __align__(16) u16 Blds[256 * 40];    // 20 KB
    __shared__ float zc3[3][64];
    __shared__ int dstc[64], srcc[64];
    __shared__ float stg[4][32][65];                // 33.3 KB
    const int tid = threadIdx.x;
    const int eb = blockIdx.x * 64;

    if (tid < 64){
        srcc[tid] = srcS[eb + tid];
        dstc[tid] = dstS[eb + tid];
    }
    int tz = tid - 64;
    if (tz >= 0 && tz < 192){
        int g = tz / 64, e = tz % 64;
        zc3[g][e] = zS[(size_t)g * NE + eb + e];
    }
    __syncthreads();

    const int wave = tid >> 6, lane = tid & 63;
    const int quad = lane >> 4, l16 = lane & 15;
    const int est = tid >> 2, seg = tid & 3;

    const f32x4 zero4 = {0.f, 0.f, 0.f, 0.f};
    f32x4 acc[4][4];
    #pragma unroll
    for (int r=0;r<4;r++)
        #pragma unroll
        for (int c=0;c<4;c++) acc[r][c] = zero4;

    const int d = dstc[est], s = srcc[est];

    for (int kc = 0; kc < 768; kc += 32){
        const int g  = kc >> 8;
        const int j0 = (kc & 255) + seg * 8;
        {
            uint4 ua = *reinterpret_cast<const uint4*>(&AB16[(size_t)d * 1536 + g * 512 + j0]);
            uint4 ub = *reinterpret_cast<const uint4*>(&AB16[(size_t)s * 1536 + g * 512 + 256 + j0]);
            const u16* wa = (const u16*)&ua;
            const u16* wb = (const u16*)&ub;
            float zk = zc3[g][est];
            u16 pk[8];
            #pragma unroll
            for (int i=0;i<8;i++){
                float v = zk * fmaxf(bf2f(wa[i]) + bf2f(wb[i]), 0.f);
                pk[i] = f2bf(v);
            }
            *reinterpret_cast<uint4*>(&Alds[est * 40 + seg * 8]) = *reinterpret_cast<uint4*>(pk);
        }
        #pragma unroll
        for (int i=0;i<4;i++){
            int n = (tid >> 2) + i * 64;
            uint4 w = *reinterpret_cast<const uint4*>(&W2T[(size_t)n * 768 + kc + seg * 8]);
            *reinterpret_cast<uint4*>(&Blds[n * 40 + seg * 8]) = w;
        }
        __syncthreads();
        bf16x8 af[4], bfr[4];
        #pragma unroll
        for (int r=0;r<4;r++)
            af[r] = *reinterpret_cast<const bf16x8*>(&Alds[(r*16 + l16) * 40 + quad * 8]);
        #pragma unroll
        for (int c=0;c<4;c++)
            bfr[c] = *reinterpret_cast<const bf16x8*>(&Blds[(wave*64 + c*16 + l16) * 40 + quad * 8]);
        #pragma unroll
        for (int r=0;r<4;r++)
            #pragma unroll
            for (int c=0;c<4;c++)
                acc[r][c] = __builtin_amdgcn_mfma_f32_16x16x32_bf16(af[r], bfr[c], acc[r][c], 0, 0, 0);
        __syncthreads();
    }
    // add bias term sum_g z_g*b2[g][col] per (edge,col)
    #pragma unroll
    for (int c=0;c<4;c++){
        int col = wave*64 + c*16 + l16;
        float b20 = b2[col], b21 = b2[256 + col], b22 = b2[512 + col];
        #pragma unroll
        for (int r=0;r<4;r++){
            #pragma unroll
            for (int reg=0;reg<4;reg++){
                int e = r*16 + quad*4 + reg;
                acc[r][c][reg] += zc3[0][e]*b20 + zc3[1][e]*b21 + zc3[2][e]*b22;
            }
        }
    }
    // segment-reduce epilogue: stage 32 edges at a time, lane owns one column
    float sum = 0.f;
    int cur_d = -1;
    const int colg = wave*64 + lane;
    #pragma unroll
    for (int chunk = 0; chunk < 2; chunk++){
        #pragma unroll
        for (int rr = 0; rr < 2; rr++){
            int r = chunk*2 + rr;
            #pragma unroll
            for (int c=0;c<4;c++)
                #pragma unroll
                for (int reg=0;reg<4;reg++){
                    int el = rr*16 + quad*4 + reg;
                    stg[wave][el][c*16 + l16] = acc[r][c][reg];
                }
        }
        __syncthreads();
        for (int e = 0; e < 32; e++){
            int eg = chunk*32 + e;
            int dn = dstc[eg];
            float v = stg[wave][e][lane];
            if (dn != cur_d){
                if (cur_d >= 0) atomicAdd(&m_acc[(size_t)cur_d * 256 + colg], sum);
                cur_d = dn; sum = v;
            } else {
                sum += v;
            }
        }
        __syncthreads();
    }
    if (cur_d >= 0) atomicAdd(&m_acc[(size_t)cur_d * 256 + colg], sum);
}

// Fused GRU gates + output head. One block per node (256 threads = 256 hidden).
__global__ void gates_mu_k(
    const float* __restrict__ gh, const u16* __restrict__ m16,
    const float* __restrict__ x, const float* __restrict__ Wih,
    const float* __restrict__ bih, const float* __restrict__ Wo,
    const float* __restrict__ bo, float* __restrict__ prev,
    u16* __restrict__ h16, void* __restrict__ out,
    const int* __restrict__ flag, int t)
{
    const int n = blockIdx.x;
    const int j = threadIdx.x;
    const int idx = n * 256 + j;
    float inp[6];
    if (t < TTEACH){
        #pragma unroll
        for (int c=0;c<6;c++) inp[c] = x[(size_t)n * NFEAT + t * 6 + c];
    } else {
        #pragma unroll
        for (int c=0;c<6;c++) inp[c] = prev[n * 6 + c];
    }
    float m = bf2f(m16[idx]);
    float gxr = bih[j], gxz = bih[256 + j], gxn = bih[512 + j];
    #pragma unroll
    for (int c=0;c<6;c++){
        gxr += inp[c] * Wih[j * 6 + c];
        gxz += inp[c] * Wih[(256 + j) * 6 + c];
        gxn += inp[c] * Wih[(512 + j) * 6 + c];
    }
    float ghr = gh[(size_t)n * 768 + j];
    float ghz = gh[(size_t)n * 768 + 256 + j];
    float ghn = gh[(size_t)n * 768 + 512 + j];
    float r  = 1.f / (1.f + __expf(-(gxr + ghr)));
    float zg = 1.f / (1.f + __expf(-(gxz + ghz)));
    float nn = tanhf(gxn + r * ghn);
    float hv = (1.f - zg) * nn + zg * m;
    h16[idx] = f2bf(hv);
    // output head: mu = inp + relu(h @ Wo + bo)
    __shared__ float hl[256];
    __shared__ float part[6][9];
    hl[j] = hv;
    __syncthreads();
    if (j < 48){
        int c = j >> 3, p = j & 7;
        float s = 0.f;
        #pragma unroll 8
        for (int q = 0; q < 32; q++){
            int jj = p*32 + q;
            s += hl[jj] * Wo[jj * 6 + c];
        }
        part[c][p] = s;
    }
    __syncthreads();
    if (j < 6){
        float s = bo[j];
        #pragma unroll
        for (int p = 0; p < 8; p++) s += part[j][p];
        float mu = inp[j] + fmaxf(s, 0.f);
        if (*flag) ((float*)out)[(size_t)n * NFEAT + t * 6 + j] = mu;
        else       ((u16*)out)[(size_t)n * NFEAT + t * 6 + j] = f2bf(mu);
        prev[n * 6 + j] = mu;
    }
}

extern "C" void kernel_launch(void* const* d_in, const int* in_sizes, int n_in,
                              void* d_out, int out_size, void* d_ws, size_t ws_size,
                              hipStream_t stream)
{
    const void* x_r   = d_in[0];
    const int*  ei    = (const int*)d_in[1];
    const void* z_r   = d_in[2];
    const void* Wf_r  = d_in[3];
    const void* bf_r  = d_in[4];
    const void* W1_r  = d_in[5];
    const void* b1_r  = d_in[6];
    const void* W2_r  = d_in[7];
    const void* b2_r  = d_in[8];
    const void* Wih_r = d_in[9];
    const void* bih_r = d_in[10];
    const void* Whh_r = d_in[11];
    const void* bhh_r = d_in[12];
    const void* Wo_r  = d_in[13];
    const void* bo_r  = d_in[14];

    char* ws = (char*)d_ws;
    size_t off = 0;
    auto alloc = [&](size_t bytes){
        void* p = ws + off;
        off += (bytes + 255) & ~(size_t)255;
        return p;
    };
    u16*   h16   = (u16*)  alloc((size_t)NN * HID * 2);
    float* prev  = (float*)alloc((size_t)NN * 6 * 4);
    u16*   fh16  = (u16*)  alloc((size_t)NN * NFEAT * 2);
    u16*   AB16  = (u16*)  alloc((size_t)NN * 1536 * 2);
    float* m_acc = (float*)alloc((size_t)NN * HID * 4);
    u16*   m16   = (u16*)  alloc((size_t)NN * HID * 2);
    float* gh    = (float*)alloc((size_t)NN * 768 * 4);
    float* invc  = (float*)alloc((size_t)NN * 4);
    int*   cnt   = (int*)  alloc((size_t)NN * 4);
    int*   binoff= (int*)  alloc((size_t)(NN + 1) * 4);
    int*   curw  = (int*)  alloc((size_t)NN * 4);
    u16*   WfT   = (u16*)  alloc((size_t)192 * 256 * 2);
    u16*   W1T   = (u16*)  alloc((size_t)1536 * 192 * 2);
    u16*   Whh16 = (u16*)  alloc((size_t)768 * 256 * 2);
    u16*   W2T   = (u16*)  alloc((size_t)256 * 768 * 2);
    int*   src32 = (int*)  alloc((size_t)NE * 4);
    int*   dst32 = (int*)  alloc((size_t)NE * 4);
    int*   srcS  = (int*)  alloc((size_t)NE * 4);
    int*   dstS  = (int*)  alloc((size_t)NE * 4);
    float* zS    = (float*)alloc((size_t)3 * NE * 4);
    int*   fdt   = (int*)  alloc(256);
    int*   fidx  = (int*)  alloc(256);
    float* xc   = (float*)alloc((size_t)NN * NFEAT * 4);
    float* zc   = (float*)alloc((size_t)NE * 4 * 4);
    float* Wfc  = (float*)alloc((size_t)256 * 192 * 4);
    float* bfc  = (float*)alloc(192 * 4);
    float* W1c  = (float*)alloc((size_t)3 * 384 * 256 * 4);
    float* b1c  = (float*)alloc(768 * 4);
    float* W2c  = (float*)alloc((size_t)3 * 256 * 256 * 4);
    float* b2c  = (float*)alloc(768 * 4);
    float* Wihc = (float*)alloc((size_t)768 * 6 * 4);
    float* bihc = (float*)alloc(768 * 4);
    float* Whhc = (float*)alloc((size_t)768 * 256 * 4);
    float* bhhc = (float*)alloc(768 * 4);
    float* Woc  = (float*)alloc((size_t)256 * 6 * 4);
    float* boc  = (float*)alloc(6 * 4);

    detect_f32<<<1, 1, 0, stream>>>((const u16*)z_r, fdt);
    detect_i64<<<1, 1, 0, stream>>>(ei, fidx);
    copy_edges<<<(NE + 255)/256, 256, 0, stream>>>(ei, fidx, src32, dst32);

    auto conv = [&](const void* in, float* outp, int n){
        conv_f32<<<(n + 255)/256, 256, 0, stream>>>(in, outp, n, fdt);
    };
    conv(x_r,   xc,   NN * NFEAT);
    conv(z_r,   zc,   NE * 4);
    conv(Wf_r,  Wfc,  256 * 192);
    conv(bf_r,  bfc,  192);
    conv(W1_r,  W1c,  3 * 384 * 256);
    conv(b1_r,  b1c,  768);
    conv(W2_r,  W2c,  3 * 256 * 256);
    conv(b2_r,  b2c,  768);
    conv(Wih_r, Wihc, 768 * 6);
    conv(bih_r, bihc, 768);
    conv(Whh_r, Whhc, 768 * 256);
    conv(bhh_r, bhhc, 768);
    conv(Wo_r,  Woc,  256 * 6);
    conv(bo_r,  boc,  6);

    fill_f32<<<(NN*HID/2 + 255)/256, 256, 0, stream>>>((float*)h16, 0.f, NN*HID/2);
    fill_f32<<<(NN*6 + 255)/256, 256, 0, stream>>>(prev, 0.f, NN*6);
    fill_f32<<<(NN*HID + 255)/256, 256, 0, stream>>>(m_acc, 0.f, NN*HID);
    fill_i32<<<(NN + 255)/256, 256, 0, stream>>>(cnt, 0, NN);
    degree_k<<<(NE + 255)/256, 256, 0, stream>>>(dst32, cnt, NE);
    invcnt_k<<<(NN + 255)/256, 256, 0, stream>>>(cnt, invc, NN);
    scan_k<<<1, 1024, 0, stream>>>(cnt, binoff);
    copy_i32<<<(NN + 255)/256, 256, 0, stream>>>(binoff, curw, NN);
    scatter_k<<<(NE + 255)/256, 256, 0, stream>>>(src32, dst32, zc, curw, srcS, dstS, zS);
    build_wft<<<(256*192 + 255)/256, 256, 0, stream>>>(Wfc, WfT);
    build_w1t<<<(1536*192 + 255)/256, 256, 0, stream>>>(W1c, W1T);
    conv_bf16<<<(768*256 + 255)/256, 256, 0, stream>>>(Whhc, Whh16, 768*256);
    build_w2t<<<(768*256 + 255)/256, 256, 0, stream>>>(W2c, W2T);

    for (int t = 0; t < TS; t++){
        gemm_mfma<0><<<dim3(40, 3), 256, 0, stream>>>(h16, WfT, bfc, nullptr, fh16, NN, 256, NFEAT);
        gemm_mfma<1><<<dim3(40, 24), 256, 0, stream>>>(fh16, W1T, b1c, nullptr, AB16, NN, NFEAT, 1536);
        edge_mfma<<<2500, 256, 0, stream>>>(AB16, W2T, b2c, zS, srcS, dstS, m_acc);
        mscale_k<<<(NN*HID + 255)/256, 256, 0, stream>>>(m_acc, invc, m16);
        gemm_mfma<2><<<dim3(40, 12), 256, 0, stream>>>(m16, Whh16, bhhc, gh, nullptr, NN, 256, 768);
        gates_mu_k<<<NN, 256, 0, stream>>>(gh, m16, xc, Wihc, bihc, Woc, boc, prev, h16, d_out, fdt, t);
    }
}